// Round 18
// baseline (471.577 us; speedup 1.0000x reference)
//
#include <hip/hip_runtime.h>
#include <hip/hip_cooperative_groups.h>
#include <stdint.h>

namespace cg = cooperative_groups;

#define CONF_T 0.05f
#define KSEL 1000
#define CAND_CAP 2048
#define ROWS 128
#define GRID 256
#define TPB 1024
#define SH_A 21          // pass-A window: bits[31:21]
#define SH_B 10          // pass-B window: bits[20:10]
#define NSL 32           // slices per batch in P2-P4 (GRID / B)

// ---- wave-parallel crossing over 2048 LDS bins: find bin v (desc) where cumulative
// from top crosses rem; res = {v, rem_in_bin}. Entry+exit __syncthreads.
__device__ __forceinline__ void crossing2048(
    const uint32_t* __restrict__ hh, uint32_t rem, volatile uint32_t* __restrict__ res)
{
    __syncthreads();
    if (threadIdx.x < 64) {
        const int lane = threadIdx.x;
        uint32_t s = 0;
        #pragma unroll 8
        for (int j = 0; j < 32; ++j) s += hh[lane * 32 + j];
        uint32_t suf = s;
        #pragma unroll
        for (int off = 1; off < 64; off <<= 1) {
            uint32_t t = __shfl_down(suf, off);
            if (lane + off < 64) suf += t;
        }
        unsigned long long m = __ballot(suf >= rem);
        int L = (m == 0) ? 0 : (63 - __clzll(m));
        uint32_t cum_above = (L < 63) ? __shfl(suf, L + 1) : 0u;

        uint32_t binv = (lane < 32) ? hh[L * 32 + lane] : 0u;
        uint32_t suf2 = binv;
        #pragma unroll
        for (int off = 1; off < 32; off <<= 1) {
            uint32_t t = __shfl_down(suf2, off);
            if (lane + off < 32) suf2 += t;
        }
        unsigned long long m2 = __ballot(lane < 32 && (cum_above + suf2) >= rem);
        int j = (m2 == 0) ? 0 : (63 - __clzll(m2));
        uint32_t above2 = cum_above + ((j < 31) ? __shfl(suf2, j + 1) : 0u);
        if (lane == 0) {
            res[0] = (uint32_t)(L * 32 + j);
            res[1] = rem - above2;
        }
    }
    __syncthreads();
}

__global__ __launch_bounds__(TPB) void fused_coop_kernel(
    const float* __restrict__ probs, const float* __restrict__ anchors,
    const float* __restrict__ offsets, const float* __restrict__ window,
    float* __restrict__ sc, int* __restrict__ cls,
    uint32_t* __restrict__ histA, uint32_t* __restrict__ histB,
    uint32_t* __restrict__ gcnt, uint64_t* __restrict__ gcand,
    float* __restrict__ out, int N, int B, int total)
{
    cg::grid_group gg = cg::this_grid();
    __shared__ float    tile[ROWS * 81];
    __shared__ uint32_t lh[2048];
    __shared__ uint32_t hh[2048];
    __shared__ uint32_t res[2];
    __shared__ uint64_t cand[CAND_CAP];

    const int tid = threadIdx.x;
    const int bid = blockIdx.x;

    // ---------------- P0: zero histA | histB | gcnt ----------------
    {
        const int nz = B * 2048 * 2 + B;
        for (int i = bid * TPB + tid; i < nz; i += GRID * TPB) {
            if      (i < B * 2048)     histA[i] = 0u;
            else if (i < B * 2048 * 2) histB[i - B * 2048] = 0u;
            else                       gcnt[i - B * 2048 * 2] = 0u;
        }
    }
    __threadfence();
    gg.sync();

    // ---------------- P1: LDS-tiled argmax + packed histA ----------------
    const int ntiles = (total + ROWS - 1) / ROWS;
    for (int t = bid; t < ntiles; t += GRID) {
        const int r0 = t * ROWS;
        const int rows_here = min(ROWS, total - r0);
        const int b0 = r0 / N;

        for (int i = tid; i < 2048; i += TPB) lh[i] = 0u;
        const float4* src = reinterpret_cast<const float4*>(probs + (size_t)r0 * 80);
        const int nf4 = rows_here * 20;
        for (int f = tid; f < nf4; f += TPB) {
            float4 v = src[f];
            int fo = f * 4; int row = fo / 80; int col = fo - row * 80;
            float* dst = &tile[row * 81 + col];
            dst[0] = v.x; dst[1] = v.y; dst[2] = v.z; dst[3] = v.w;
        }
        __syncthreads();
        if (tid < rows_here) {
            const float* row = &tile[tid * 81];
            float best = row[0]; int bc = 0;
            #pragma unroll
            for (int j = 1; j < 80; ++j) {
                float v = row[j];
                if (v > best) { best = v; bc = j; }   // first-max-wins
            }
            const int gr = r0 + tid;
            sc[gr]  = best;
            cls[gr] = bc;
            const int sel = (gr / N) - b0;            // 0 or 1 (tile straddles <= 2 batches)
            atomicAdd(&lh[__float_as_uint(best) >> SH_A], 1u << (16 * sel));
        }
        __syncthreads();
        for (int i = tid; i < 2048; i += TPB) {
            uint32_t v = lh[i];
            if (v & 0xFFFFu) atomicAdd(&histA[(size_t)b0 * 2048 + i], v & 0xFFFFu);
            uint32_t hi2 = v >> 16;
            if (hi2)         atomicAdd(&histA[(size_t)(b0 + 1) * 2048 + i], hi2);
        }
        __syncthreads();   // protect tile/lh reuse next iteration
    }
    __threadfence();
    gg.sync();

    const int b   = bid / NSL;
    const int chn = bid % NSL;
    const float4* s4 = reinterpret_cast<const float4*>(sc + (size_t)b * N);
    const int n4  = N >> 2;
    const int cf4 = (n4 + NSL - 1) / NSL;
    const int fb  = chn * cf4;
    const int fe  = min(fb + cf4, n4);

    // ---------------- P2: pass-B histogram ----------------
    {
        for (int i = tid; i < 2048; i += TPB) hh[i] = histA[(size_t)b * 2048 + i];
        crossing2048(hh, KSEL, res);
        const uint32_t vA = res[0];

        for (int i = tid; i < 2048; i += TPB) lh[i] = 0u;
        __syncthreads();
        for (int f = fb + tid; f < fe; f += TPB) {
            float4 v = s4[f];
            #pragma unroll
            for (int j = 0; j < 4; ++j) {
                uint32_t bits = __float_as_uint(j==0 ? v.x : j==1 ? v.y : j==2 ? v.z : v.w);
                if ((bits >> SH_A) == vA)
                    atomicAdd(&lh[(bits >> SH_B) & 0x7FFu], 1u);
            }
        }
        __syncthreads();
        for (int i = tid; i < 2048; i += TPB)
            if (lh[i]) atomicAdd(&histB[(size_t)b * 2048 + i], lh[i]);
    }
    __threadfence();
    gg.sync();

    // ---------------- P3: gather candidates ----------------
    {
        for (int i = tid; i < 2048; i += TPB) hh[i] = histA[(size_t)b * 2048 + i];
        crossing2048(hh, KSEL, res);
        const uint32_t vA = res[0], remA = res[1];
        for (int i = tid; i < 2048; i += TPB) hh[i] = histB[(size_t)b * 2048 + i];
        crossing2048(hh, remA, res);
        const uint32_t t_lo = (vA << SH_A) | (res[0] << SH_B);

        for (int f = fb + tid; f < fe; f += TPB) {
            float4 v = s4[f];
            #pragma unroll
            for (int j = 0; j < 4; ++j) {
                uint32_t bits = __float_as_uint(j==0 ? v.x : j==1 ? v.y : j==2 ? v.z : v.w);
                if (bits >= t_lo) {
                    uint32_t pos = atomicAdd(&gcnt[b], 1u);
                    if (pos < CAND_CAP)
                        gcand[(size_t)b * CAND_CAP + pos] =
                            ((uint64_t)(~bits) << 32) | (uint64_t)(uint32_t)(4*f + j);  // ties: ASC idx
                }
            }
        }
    }
    __threadfence();
    gg.sync();

    // ---------------- P4: exact rank + decode + write (sliced) ----------------
    {
        uint32_t G = gcnt[b];
        if (G > CAND_CAP) G = CAND_CAP;
        for (uint32_t i = tid; i < G; i += TPB) cand[i] = gcand[(size_t)b * CAND_CAP + i];
        __syncthreads();

        const uint32_t per = (G + NSL - 1) / NSL;
        const uint32_t c0 = chn * per;
        const uint32_t c1 = min(c0 + per, G);

        const float wy1 = window[0], wx1 = window[1], wy2 = window[2], wx2 = window[3];
        const int BK = B * KSEL;
        float* o_ai = out;             // [B,K,2] (b, idx)
        float* o_bx = out + 2 * BK;    // [B,K,4]
        float* o_cl = out + 6 * BK;
        float* o_sc = out + 7 * BK;
        float* o_vd = out + 8 * BK;

        for (uint32_t c = c0 + tid; c < c1; c += TPB) {
            const uint64_t kc = cand[c];
            uint32_t r = 0;
            for (uint32_t j = 0; j < G; ++j) r += (cand[j] < kc) ? 1u : 0u;
            if (r >= KSEL) continue;

            uint32_t idx   = (uint32_t)kc;
            uint32_t sbits = ~(uint32_t)(kc >> 32);
            float score    = __uint_as_float(sbits);

            size_t base = (size_t)b * N + idx;
            const float4 a = *reinterpret_cast<const float4*>(anchors + base * 4);
            const float4 o = *reinterpret_cast<const float4*>(offsets + base * 4);

            float h  = a.z - a.x;
            float w  = a.w - a.y;
            float cy = a.x + 0.5f * h + o.x * h;
            float cx = a.y + 0.5f * w + o.y * w;
            float hh2 = h * expf(o.z);
            float ww  = w * expf(o.w);
            float y1 = fminf(fmaxf(cy - 0.5f * hh2, wy1), wy2);
            float x1 = fminf(fmaxf(cx - 0.5f * ww,  wx1), wx2);
            float y2 = fminf(fmaxf(cy + 0.5f * hh2, wy1), wy2);
            float x2 = fminf(fmaxf(cx + 0.5f * ww,  wx1), wx2);

            int ok = b * KSEL + (int)r;
            o_ai[ok*2 + 0] = (float)b;
            o_ai[ok*2 + 1] = (float)idx;
            o_bx[ok*4 + 0] = y1;
            o_bx[ok*4 + 1] = x1;
            o_bx[ok*4 + 2] = y2;
            o_bx[ok*4 + 3] = x2;
            o_cl[ok] = (float)cls[base];
            o_sc[ok] = score;
            o_vd[ok] = (score > CONF_T) ? 1.0f : 0.0f;
        }
    }
}

extern "C" void kernel_launch(void* const* d_in, const int* in_sizes, int n_in,
                              void* d_out, int out_size, void* d_ws, size_t ws_size,
                              hipStream_t stream)
{
    const float* anchors = (const float*)d_in[0];
    const float* probs   = (const float*)d_in[1];
    const float* offsets = (const float*)d_in[2];
    const float* window  = (const float*)d_in[3];

    int B = out_size / (9 * KSEL);
    int N = in_sizes[0] / (B * 4);
    int total = B * N;

    char* p = (char*)d_ws;
    float*    sc    = (float*)p;     p += (size_t)total * 4;
    int*      cls   = (int*)p;       p += (size_t)total * 4;
    uint64_t* gcand = (uint64_t*)p;  p += (size_t)B * CAND_CAP * 8;
    uint32_t* histA = (uint32_t*)p;  p += (size_t)B * 2048 * 4;
    uint32_t* histB = (uint32_t*)p;  p += (size_t)B * 2048 * 4;
    uint32_t* gcnt  = (uint32_t*)p;

    float* outp = (float*)d_out;
    void* args[] = { (void*)&probs, (void*)&anchors, (void*)&offsets, (void*)&window,
                     (void*)&sc, (void*)&cls, (void*)&histA, (void*)&histB,
                     (void*)&gcnt, (void*)&gcand, (void*)&outp,
                     (void*)&N, (void*)&B, (void*)&total };

    hipLaunchCooperativeKernel((const void*)fused_coop_kernel,
                               dim3(GRID), dim3(TPB), args, 0, stream);
}

// Round 19
// 98.343 us; speedup vs baseline: 4.7952x; 4.7952x over previous
//
#include <hip/hip_runtime.h>
#include <hip/hip_bf16.h>
#include <stdint.h>

#define CONF_T 0.05f
#define KSEL 1000
#define CAND_CAP 2048
#define ROWS 128
#define T1 256
#define SH_A 21          // pass-A window: bits[31:21] (11 bits, 2048 bins)
#define SH_B 10          // pass-B window: bits[20:10] (11 bits, 2048 bins)

// ---------------- Kernel 0: zero histA (avoid runtime fillBuffer graph node) ----------
__global__ __launch_bounds__(256) void zero_kernel(uint32_t* __restrict__ p, int n)
{
    int gid = blockIdx.x * blockDim.x + threadIdx.x;
    if (gid < n) p[gid] = 0u;
}

// ---------------- Kernel 1: LDS-staged argmax + fused pass-A histogram (R16, verified) ----
__global__ __launch_bounds__(T1) void score_argmax_hist_kernel(
    const float* __restrict__ probs, float* __restrict__ sc, int* __restrict__ cls,
    uint32_t* __restrict__ histA, int total, int N)
{
    __shared__ float tile[ROWS * 81];
    __shared__ uint32_t lh[2048];        // packed dual-batch: lo16 = b0, hi16 = b0+1
    const int r0  = blockIdx.x * ROWS;
    const int tid = threadIdx.x;
    const int rows_here = min(ROWS, total - r0);
    const int b0 = r0 / N;

    for (int i = tid; i < 2048; i += T1) lh[i] = 0u;

    const float4* src = reinterpret_cast<const float4*>(probs + (size_t)r0 * 80);
    const int nf4 = rows_here * 20;
    for (int f = tid; f < nf4; f += T1) {
        float4 v = src[f];
        int fo  = f * 4;
        int row = fo / 80;
        int col = fo - row * 80;
        float* dst = &tile[row * 81 + col];
        dst[0] = v.x; dst[1] = v.y; dst[2] = v.z; dst[3] = v.w;
    }
    __syncthreads();

    if (tid < rows_here) {
        const float* row = &tile[tid * 81];
        float best = row[0]; int bc = 0;
        #pragma unroll
        for (int j = 1; j < 80; ++j) {
            float v = row[j];
            if (v > best) { best = v; bc = j; }   // first-max-wins
        }
        const int gr = r0 + tid;
        sc[gr]  = best;
        cls[gr] = bc;
        const int sel = (gr / N) - b0;            // 0 or 1 (block straddles <= 2 batches)
        atomicAdd(&lh[__float_as_uint(best) >> SH_A], 1u << (16 * sel));
    }
    __syncthreads();

    for (int i = tid; i < 2048; i += T1) {
        uint32_t v = lh[i];
        if (v & 0xFFFFu) atomicAdd(&histA[(size_t)b0 * 2048 + i], v & 0xFFFFu);
        uint32_t hi = v >> 16;
        if (hi)          atomicAdd(&histA[(size_t)(b0 + 1) * 2048 + i], hi);
    }
}

// ---- wave-parallel crossing over 2048 LDS bins (R17/R18, verified): find bin v (desc)
// where cumulative from top crosses rem; res = {v, rem_in_bin}.
__device__ __forceinline__ void crossing2048(
    const uint32_t* __restrict__ hh, uint32_t rem, volatile uint32_t* __restrict__ res)
{
    __syncthreads();
    if (threadIdx.x < 64) {
        const int lane = threadIdx.x;
        uint32_t s = 0;
        #pragma unroll 8
        for (int j = 0; j < 32; ++j) s += hh[lane * 32 + j];
        uint32_t suf = s;
        #pragma unroll
        for (int off = 1; off < 64; off <<= 1) {
            uint32_t t = __shfl_down(suf, off);
            if (lane + off < 64) suf += t;
        }
        unsigned long long m = __ballot(suf >= rem);
        int L = (m == 0) ? 0 : (63 - __clzll(m));
        uint32_t cum_above = (L < 63) ? __shfl(suf, L + 1) : 0u;

        uint32_t binv = (lane < 32) ? hh[L * 32 + lane] : 0u;
        uint32_t suf2 = binv;
        #pragma unroll
        for (int off = 1; off < 32; off <<= 1) {
            uint32_t t = __shfl_down(suf2, off);
            if (lane + off < 32) suf2 += t;
        }
        unsigned long long m2 = __ballot(lane < 32 && (cum_above + suf2) >= rem);
        int j = (m2 == 0) ? 0 : (63 - __clzll(m2));
        uint32_t above2 = cum_above + ((j < 31) ? __shfl(suf2, j + 1) : 0u);
        if (lane == 0) {
            res[0] = (uint32_t)(L * 32 + j);
            res[1] = rem - above2;
        }
    }
    __syncthreads();
}

// ---------------- Kernel 2: pass-B hist + gather + exact rank + decode ----------------
__global__ __launch_bounds__(1024) void final_select_kernel(
    const float* __restrict__ scores, const int* __restrict__ cls_ws,
    const uint32_t* __restrict__ histA,
    const float* __restrict__ anchors, const float* __restrict__ offsets,
    const float* __restrict__ window, float* __restrict__ out,
    int N, int B)
{
    const int b   = blockIdx.x;
    const int tid = threadIdx.x;

    __shared__ uint32_t hh[2048];
    __shared__ uint32_t res[2];
    __shared__ uint32_t sh_vA, sh_remA, sh_cnt;
    __shared__ uint64_t cand[CAND_CAP];

    // ---- pass-A crossing (wave-parallel)
    for (int i = tid; i < 2048; i += 1024) hh[i] = histA[(size_t)b * 2048 + i];
    if (tid == 0) sh_cnt = 0u;
    crossing2048(hh, KSEL, res);
    if (tid == 0) { sh_vA = res[0]; sh_remA = res[1]; }
    __syncthreads();
    const uint32_t vA = sh_vA, remA = sh_remA;

    // ---- pass-B histogram (bits[20:10]) over elements matching prefix A
    for (int i = tid; i < 2048; i += 1024) hh[i] = 0u;
    __syncthreads();
    const float4* s4 = reinterpret_cast<const float4*>(scores + (size_t)b * N);
    const int n4 = N >> 2;
    for (int f = tid; f < n4; f += 1024) {
        float4 v = s4[f];
        #pragma unroll
        for (int j = 0; j < 4; ++j) {
            uint32_t bits = __float_as_uint(j==0 ? v.x : j==1 ? v.y : j==2 ? v.z : v.w);
            if ((bits >> SH_A) == vA)
                atomicAdd(&hh[(bits >> SH_B) & 0x7FFu], 1u);
        }
    }
    crossing2048(hh, remA, res);
    const uint32_t t_lo = (vA << SH_A) | (res[0] << SH_B);   // lower bound on Kth score bits

    // ---- gather all candidates with bits >= t_lo (exact rank fixes the rest)
    for (int f = tid; f < n4; f += 1024) {
        float4 v = s4[f];
        #pragma unroll
        for (int j = 0; j < 4; ++j) {
            uint32_t bits = __float_as_uint(j==0 ? v.x : j==1 ? v.y : j==2 ? v.z : v.w);
            if (bits >= t_lo) {
                uint32_t pos = atomicAdd(&sh_cnt, 1u);
                if (pos < CAND_CAP)
                    cand[pos] = ((uint64_t)(~bits) << 32) | (uint64_t)(uint32_t)(4*f + j);  // ties: ASC idx
            }
        }
    }
    __syncthreads();
    uint32_t G = sh_cnt;
    if (G > CAND_CAP) G = CAND_CAP;

    // ---- exact rank (keys distinct) + decode + f32 write
    const float wy1 = window[0], wx1 = window[1], wy2 = window[2], wx2 = window[3];
    const int BK = B * KSEL;
    float* o_ai = out;             // [B,K,2] (b, idx)
    float* o_bx = out + 2 * BK;    // [B,K,4]
    float* o_cl = out + 6 * BK;
    float* o_sc = out + 7 * BK;
    float* o_vd = out + 8 * BK;

    for (uint32_t c = tid; c < G; c += 1024) {
        const uint64_t kc = cand[c];
        uint32_t r = 0;
        for (uint32_t j = 0; j < G; ++j) r += (cand[j] < kc) ? 1u : 0u;
        if (r >= KSEL) continue;

        uint32_t idx   = (uint32_t)kc;
        uint32_t sbits = ~(uint32_t)(kc >> 32);
        float score    = __uint_as_float(sbits);

        size_t base = (size_t)b * N + idx;
        const float4 a = *reinterpret_cast<const float4*>(anchors + base * 4);
        const float4 o = *reinterpret_cast<const float4*>(offsets + base * 4);

        float h  = a.z - a.x;
        float w  = a.w - a.y;
        float cy = a.x + 0.5f * h + o.x * h;
        float cx = a.y + 0.5f * w + o.y * w;
        float hh2 = h * expf(o.z);
        float ww  = w * expf(o.w);
        float y1 = fminf(fmaxf(cy - 0.5f * hh2, wy1), wy2);
        float x1 = fminf(fmaxf(cx - 0.5f * ww,  wx1), wx2);
        float y2 = fminf(fmaxf(cy + 0.5f * hh2, wy1), wy2);
        float x2 = fminf(fmaxf(cx + 0.5f * ww,  wx1), wx2);

        int ok = b * KSEL + (int)r;
        o_ai[ok*2 + 0] = (float)b;
        o_ai[ok*2 + 1] = (float)idx;
        o_bx[ok*4 + 0] = y1;
        o_bx[ok*4 + 1] = x1;
        o_bx[ok*4 + 2] = y2;
        o_bx[ok*4 + 3] = x2;
        o_cl[ok] = (float)cls_ws[base];
        o_sc[ok] = score;
        o_vd[ok] = (score > CONF_T) ? 1.0f : 0.0f;
    }
}

extern "C" void kernel_launch(void* const* d_in, const int* in_sizes, int n_in,
                              void* d_out, int out_size, void* d_ws, size_t ws_size,
                              hipStream_t stream)
{
    const float* anchors = (const float*)d_in[0];
    const float* probs   = (const float*)d_in[1];
    const float* offsets = (const float*)d_in[2];
    const float* window  = (const float*)d_in[3];

    const int B = out_size / (9 * KSEL);
    const int N = in_sizes[0] / (B * 4);
    const int total = B * N;

    float*    sc    = (float*)d_ws;
    int*      cls   = (int*)((char*)d_ws + (size_t)total * 4);
    uint32_t* histA = (uint32_t*)((char*)d_ws + (size_t)total * 8);
    const int nhist = B * 2048;

    hipLaunchKernelGGL(zero_kernel, dim3((nhist + 255) / 256), dim3(256), 0, stream,
                       histA, nhist);

    hipLaunchKernelGGL(score_argmax_hist_kernel,
                       dim3((total + ROWS - 1) / ROWS), dim3(T1), 0, stream,
                       probs, sc, cls, histA, total, N);

    hipLaunchKernelGGL(final_select_kernel, dim3(B), dim3(1024), 0, stream,
                       sc, cls, histA, anchors, offsets, window,
                       (float*)d_out, N, B);
}

// Round 20
// 97.299 us; speedup vs baseline: 4.8467x; 1.0107x over previous
//
#include <hip/hip_runtime.h>
#include <hip/hip_bf16.h>
#include <stdint.h>

#define CONF_T 0.05f
#define KSEL 1000
#define CAND_CAP 2048
#define ROWS 128
#define T1 256
#define SH_A 21          // pass-A window: bits[31:21]
#define SH_B 10          // pass-B window: bits[20:10]
#define MAXIT 16         // max reg-buffered float4 iterations per thread

// ---------------- Kernel 0: zero histA ----------------
__global__ __launch_bounds__(256) void zero_kernel(uint32_t* __restrict__ p, int n)
{
    int gid = blockIdx.x * blockDim.x + threadIdx.x;
    if (gid < n) p[gid] = 0u;
}

// ---------------- Kernel 1: LDS-staged argmax + fused pass-A histogram (verified) ----
__global__ __launch_bounds__(T1) void score_argmax_hist_kernel(
    const float* __restrict__ probs, float* __restrict__ sc, int* __restrict__ cls,
    uint32_t* __restrict__ histA, int total, int N)
{
    __shared__ float tile[ROWS * 81];
    __shared__ uint32_t lh[2048];
    const int r0  = blockIdx.x * ROWS;
    const int tid = threadIdx.x;
    const int rows_here = min(ROWS, total - r0);
    const int b0 = r0 / N;

    for (int i = tid; i < 2048; i += T1) lh[i] = 0u;

    const float4* src = reinterpret_cast<const float4*>(probs + (size_t)r0 * 80);
    const int nf4 = rows_here * 20;
    for (int f = tid; f < nf4; f += T1) {
        float4 v = src[f];
        int fo  = f * 4;
        int row = fo / 80;
        int col = fo - row * 80;
        float* dst = &tile[row * 81 + col];
        dst[0] = v.x; dst[1] = v.y; dst[2] = v.z; dst[3] = v.w;
    }
    __syncthreads();

    if (tid < rows_here) {
        const float* row = &tile[tid * 81];
        float best = row[0]; int bc = 0;
        #pragma unroll
        for (int j = 1; j < 80; ++j) {
            float v = row[j];
            if (v > best) { best = v; bc = j; }   // first-max-wins
        }
        const int gr = r0 + tid;
        sc[gr]  = best;
        cls[gr] = bc;
        const int sel = (gr / N) - b0;
        atomicAdd(&lh[__float_as_uint(best) >> SH_A], 1u << (16 * sel));
    }
    __syncthreads();

    for (int i = tid; i < 2048; i += T1) {
        uint32_t v = lh[i];
        if (v & 0xFFFFu) atomicAdd(&histA[(size_t)b0 * 2048 + i], v & 0xFFFFu);
        uint32_t hi = v >> 16;
        if (hi)          atomicAdd(&histA[(size_t)(b0 + 1) * 2048 + i], hi);
    }
}

// ---- wave-parallel crossing over 2048 LDS bins (verified) ----
__device__ __forceinline__ void crossing2048(
    const uint32_t* __restrict__ hh, uint32_t rem, volatile uint32_t* __restrict__ res)
{
    __syncthreads();
    if (threadIdx.x < 64) {
        const int lane = threadIdx.x;
        uint32_t s = 0;
        #pragma unroll 8
        for (int j = 0; j < 32; ++j) s += hh[lane * 32 + j];
        uint32_t suf = s;
        #pragma unroll
        for (int off = 1; off < 64; off <<= 1) {
            uint32_t t = __shfl_down(suf, off);
            if (lane + off < 64) suf += t;
        }
        unsigned long long m = __ballot(suf >= rem);
        int L = (m == 0) ? 0 : (63 - __clzll(m));
        uint32_t cum_above = (L < 63) ? __shfl(suf, L + 1) : 0u;

        uint32_t binv = (lane < 32) ? hh[L * 32 + lane] : 0u;
        uint32_t suf2 = binv;
        #pragma unroll
        for (int off = 1; off < 32; off <<= 1) {
            uint32_t t = __shfl_down(suf2, off);
            if (lane + off < 32) suf2 += t;
        }
        unsigned long long m2 = __ballot(lane < 32 && (cum_above + suf2) >= rem);
        int j = (m2 == 0) ? 0 : (63 - __clzll(m2));
        uint32_t above2 = cum_above + ((j < 31) ? __shfl(suf2, j + 1) : 0u);
        if (lane == 0) {
            res[0] = (uint32_t)(L * 32 + j);
            res[1] = rem - above2;
        }
    }
    __syncthreads();
}

// ---------------- Kernel 2: reg-buffered single-scan select ----------------
__global__ __launch_bounds__(1024) void final_select_kernel(
    const float* __restrict__ scores, const int* __restrict__ cls_ws,
    const uint32_t* __restrict__ histA,
    const float* __restrict__ anchors, const float* __restrict__ offsets,
    const float* __restrict__ window, float* __restrict__ out,
    int N, int B)
{
    const int b   = blockIdx.x;
    const int tid = threadIdx.x;

    __shared__ uint32_t hh[2048];
    __shared__ uint32_t res[2];
    __shared__ uint32_t sh_vA, sh_remA, sh_cnt;
    __shared__ uint64_t cand[CAND_CAP];

    const float4* s4 = reinterpret_cast<const float4*>(scores + (size_t)b * N);
    const int n4 = N >> 2;
    const int iters = (n4 - tid + 1023) / 1024;   // this thread's iteration count
    const bool reg_path = ((n4 + 1023) / 1024) <= MAXIT;

    // ---- issue ALL score loads up front (MLP: whole batch scan in flight at once)
    float4 vbuf[MAXIT];
    if (reg_path) {
        #pragma unroll
        for (int k = 0; k < MAXIT; ++k) {
            int f = tid + k * 1024;
            if (k < iters) vbuf[k] = s4[f];
        }
    }

    // ---- pass-A crossing
    for (int i = tid; i < 2048; i += 1024) hh[i] = histA[(size_t)b * 2048 + i];
    if (tid == 0) sh_cnt = 0u;
    crossing2048(hh, KSEL, res);
    if (tid == 0) { sh_vA = res[0]; sh_remA = res[1]; }
    __syncthreads();
    const uint32_t vA = sh_vA, remA = sh_remA;

    // ---- pass-B histogram from registers
    for (int i = tid; i < 2048; i += 1024) hh[i] = 0u;
    __syncthreads();
    if (reg_path) {
        #pragma unroll
        for (int k = 0; k < MAXIT; ++k) {
            if (k < iters) {
                float4 v = vbuf[k];
                #pragma unroll
                for (int j = 0; j < 4; ++j) {
                    uint32_t bits = __float_as_uint(j==0 ? v.x : j==1 ? v.y : j==2 ? v.z : v.w);
                    if ((bits >> SH_A) == vA)
                        atomicAdd(&hh[(bits >> SH_B) & 0x7FFu], 1u);
                }
            }
        }
    } else {
        for (int f = tid; f < n4; f += 1024) {
            float4 v = s4[f];
            #pragma unroll
            for (int j = 0; j < 4; ++j) {
                uint32_t bits = __float_as_uint(j==0 ? v.x : j==1 ? v.y : j==2 ? v.z : v.w);
                if ((bits >> SH_A) == vA)
                    atomicAdd(&hh[(bits >> SH_B) & 0x7FFu], 1u);
            }
        }
    }
    crossing2048(hh, remA, res);
    const uint32_t t_lo = (vA << SH_A) | (res[0] << SH_B);

    // ---- gather from registers
    if (reg_path) {
        #pragma unroll
        for (int k = 0; k < MAXIT; ++k) {
            if (k < iters) {
                float4 v = vbuf[k];
                int f = tid + k * 1024;
                #pragma unroll
                for (int j = 0; j < 4; ++j) {
                    uint32_t bits = __float_as_uint(j==0 ? v.x : j==1 ? v.y : j==2 ? v.z : v.w);
                    if (bits >= t_lo) {
                        uint32_t pos = atomicAdd(&sh_cnt, 1u);
                        if (pos < CAND_CAP)
                            cand[pos] = ((uint64_t)(~bits) << 32) | (uint64_t)(uint32_t)(4*f + j);
                    }
                }
            }
        }
    } else {
        for (int f = tid; f < n4; f += 1024) {
            float4 v = s4[f];
            #pragma unroll
            for (int j = 0; j < 4; ++j) {
                uint32_t bits = __float_as_uint(j==0 ? v.x : j==1 ? v.y : j==2 ? v.z : v.w);
                if (bits >= t_lo) {
                    uint32_t pos = atomicAdd(&sh_cnt, 1u);
                    if (pos < CAND_CAP)
                        cand[pos] = ((uint64_t)(~bits) << 32) | (uint64_t)(uint32_t)(4*f + j);
                }
            }
        }
    }
    __syncthreads();
    uint32_t G = sh_cnt;
    if (G > CAND_CAP) G = CAND_CAP;

    // ---- exact rank + decode + f32 write (verified)
    const float wy1 = window[0], wx1 = window[1], wy2 = window[2], wx2 = window[3];
    const int BK = B * KSEL;
    float* o_ai = out;
    float* o_bx = out + 2 * BK;
    float* o_cl = out + 6 * BK;
    float* o_sc = out + 7 * BK;
    float* o_vd = out + 8 * BK;

    for (uint32_t c = tid; c < G; c += 1024) {
        const uint64_t kc = cand[c];
        uint32_t r = 0;
        for (uint32_t j = 0; j < G; ++j) r += (cand[j] < kc) ? 1u : 0u;
        if (r >= KSEL) continue;

        uint32_t idx   = (uint32_t)kc;
        uint32_t sbits = ~(uint32_t)(kc >> 32);
        float score    = __uint_as_float(sbits);

        size_t base = (size_t)b * N + idx;
        const float4 a = *reinterpret_cast<const float4*>(anchors + base * 4);
        const float4 o = *reinterpret_cast<const float4*>(offsets + base * 4);

        float h  = a.z - a.x;
        float w  = a.w - a.y;
        float cy = a.x + 0.5f * h + o.x * h;
        float cx = a.y + 0.5f * w + o.y * w;
        float hh2 = h * expf(o.z);
        float ww  = w * expf(o.w);
        float y1 = fminf(fmaxf(cy - 0.5f * hh2, wy1), wy2);
        float x1 = fminf(fmaxf(cx - 0.5f * ww,  wx1), wx2);
        float y2 = fminf(fmaxf(cy + 0.5f * hh2, wy1), wy2);
        float x2 = fminf(fmaxf(cx + 0.5f * ww,  wx1), wx2);

        int ok = b * KSEL + (int)r;
        o_ai[ok*2 + 0] = (float)b;
        o_ai[ok*2 + 1] = (float)idx;
        o_bx[ok*4 + 0] = y1;
        o_bx[ok*4 + 1] = x1;
        o_bx[ok*4 + 2] = y2;
        o_bx[ok*4 + 3] = x2;
        o_cl[ok] = (float)cls_ws[base];
        o_sc[ok] = score;
        o_vd[ok] = (score > CONF_T) ? 1.0f : 0.0f;
    }
}

extern "C" void kernel_launch(void* const* d_in, const int* in_sizes, int n_in,
                              void* d_out, int out_size, void* d_ws, size_t ws_size,
                              hipStream_t stream)
{
    const float* anchors = (const float*)d_in[0];
    const float* probs   = (const float*)d_in[1];
    const float* offsets = (const float*)d_in[2];
    const float* window  = (const float*)d_in[3];

    const int B = out_size / (9 * KSEL);
    const int N = in_sizes[0] / (B * 4);
    const int total = B * N;

    float*    sc    = (float*)d_ws;
    int*      cls   = (int*)((char*)d_ws + (size_t)total * 4);
    uint32_t* histA = (uint32_t*)((char*)d_ws + (size_t)total * 8);
    const int nhist = B * 2048;

    hipLaunchKernelGGL(zero_kernel, dim3((nhist + 255) / 256), dim3(256), 0, stream,
                       histA, nhist);

    hipLaunchKernelGGL(score_argmax_hist_kernel,
                       dim3((total + ROWS - 1) / ROWS), dim3(T1), 0, stream,
                       probs, sc, cls, histA, total, N);

    hipLaunchKernelGGL(final_select_kernel, dim3(B), dim3(1024), 0, stream,
                       sc, cls, histA, anchors, offsets, window,
                       (float*)d_out, N, B);
}

// Round 21
// 88.128 us; speedup vs baseline: 5.3511x; 1.1041x over previous
//
#include <hip/hip_runtime.h>
#include <hip/hip_bf16.h>
#include <stdint.h>

#define CONF_T 0.05f
#define KSEL 1000
#define CAND_CAP 2048
#define ROWS 128
#define T1 256
#define SH_A 21
#define SH_B 10
#define MAXIT 16

// ---------------- Kernel 0: zero histA ----------------
__global__ __launch_bounds__(256) void zero_kernel(uint32_t* __restrict__ p, int n)
{
    int gid = blockIdx.x * blockDim.x + threadIdx.x;
    if (gid < n) p[gid] = 0u;
}

// ---------------- Kernel 1: LDS-staged argmax + fused pass-A histogram (verified) ----
__global__ __launch_bounds__(T1) void score_argmax_hist_kernel(
    const float* __restrict__ probs, float* __restrict__ sc, int* __restrict__ cls,
    uint32_t* __restrict__ histA, int total, int N)
{
    __shared__ float tile[ROWS * 81];
    __shared__ uint32_t lh[2048];
    const int r0  = blockIdx.x * ROWS;
    const int tid = threadIdx.x;
    const int rows_here = min(ROWS, total - r0);
    const int b0 = r0 / N;

    for (int i = tid; i < 2048; i += T1) lh[i] = 0u;

    const float4* src = reinterpret_cast<const float4*>(probs + (size_t)r0 * 80);
    const int nf4 = rows_here * 20;
    for (int f = tid; f < nf4; f += T1) {
        float4 v = src[f];
        int fo  = f * 4;
        int row = fo / 80;
        int col = fo - row * 80;
        float* dst = &tile[row * 81 + col];
        dst[0] = v.x; dst[1] = v.y; dst[2] = v.z; dst[3] = v.w;
    }
    __syncthreads();

    if (tid < rows_here) {
        const float* row = &tile[tid * 81];
        float best = row[0]; int bc = 0;
        #pragma unroll
        for (int j = 1; j < 80; ++j) {
            float v = row[j];
            if (v > best) { best = v; bc = j; }   // first-max-wins
        }
        const int gr = r0 + tid;
        sc[gr]  = best;
        cls[gr] = bc;
        const int sel = (gr / N) - b0;
        atomicAdd(&lh[__float_as_uint(best) >> SH_A], 1u << (16 * sel));
    }
    __syncthreads();

    for (int i = tid; i < 2048; i += T1) {
        uint32_t v = lh[i];
        if (v & 0xFFFFu) atomicAdd(&histA[(size_t)b0 * 2048 + i], v & 0xFFFFu);
        uint32_t hi = v >> 16;
        if (hi)          atomicAdd(&histA[(size_t)(b0 + 1) * 2048 + i], hi);
    }
}

// ---- wave-parallel crossing over 2048 LDS bins (verified) ----
__device__ __forceinline__ void crossing2048(
    const uint32_t* __restrict__ hh, uint32_t rem, volatile uint32_t* __restrict__ res)
{
    __syncthreads();
    if (threadIdx.x < 64) {
        const int lane = threadIdx.x;
        uint32_t s = 0;
        #pragma unroll 8
        for (int j = 0; j < 32; ++j) s += hh[lane * 32 + j];
        uint32_t suf = s;
        #pragma unroll
        for (int off = 1; off < 64; off <<= 1) {
            uint32_t t = __shfl_down(suf, off);
            if (lane + off < 64) suf += t;
        }
        unsigned long long m = __ballot(suf >= rem);
        int L = (m == 0) ? 0 : (63 - __clzll(m));
        uint32_t cum_above = (L < 63) ? __shfl(suf, L + 1) : 0u;

        uint32_t binv = (lane < 32) ? hh[L * 32 + lane] : 0u;
        uint32_t suf2 = binv;
        #pragma unroll
        for (int off = 1; off < 32; off <<= 1) {
            uint32_t t = __shfl_down(suf2, off);
            if (lane + off < 32) suf2 += t;
        }
        unsigned long long m2 = __ballot(lane < 32 && (cum_above + suf2) >= rem);
        int j = (m2 == 0) ? 0 : (63 - __clzll(m2));
        uint32_t above2 = cum_above + ((j < 31) ? __shfl(suf2, j + 1) : 0u);
        if (lane == 0) {
            res[0] = (uint32_t)(L * 32 + j);
            res[1] = rem - above2;
        }
    }
    __syncthreads();
}

// ---------------- Kernel 2: select via bitonic sort ----------------
__global__ __launch_bounds__(1024) void final_select_kernel(
    const float* __restrict__ scores, const int* __restrict__ cls_ws,
    const uint32_t* __restrict__ histA,
    const float* __restrict__ anchors, const float* __restrict__ offsets,
    const float* __restrict__ window, float* __restrict__ out,
    int N, int B)
{
    const int b    = blockIdx.x;
    const int tid  = threadIdx.x;
    const int lane = tid & 63;

    __shared__ uint32_t hh[2048];
    __shared__ uint32_t res[2];
    __shared__ uint32_t sh_vA, sh_remA, sh_cnt;
    __shared__ uint64_t cand[CAND_CAP];

    const float4* s4 = reinterpret_cast<const float4*>(scores + (size_t)b * N);
    const int n4 = N >> 2;
    const int iters = (n4 - tid + 1023) / 1024;
    const bool reg_path = ((n4 + 1023) / 1024) <= MAXIT;

    float4 vbuf[MAXIT];
    if (reg_path) {
        #pragma unroll
        for (int k = 0; k < MAXIT; ++k) {
            int f = tid + k * 1024;
            if (k < iters) vbuf[k] = s4[f];
        }
    }

    // ---- pass-A crossing
    for (int i = tid; i < 2048; i += 1024) hh[i] = histA[(size_t)b * 2048 + i];
    if (tid == 0) sh_cnt = 0u;
    crossing2048(hh, KSEL, res);
    if (tid == 0) { sh_vA = res[0]; sh_remA = res[1]; }
    __syncthreads();
    const uint32_t vA = sh_vA, remA = sh_remA;

    // ---- pass-B histogram
    for (int i = tid; i < 2048; i += 1024) hh[i] = 0u;
    __syncthreads();
    if (reg_path) {
        #pragma unroll
        for (int k = 0; k < MAXIT; ++k) {
            if (k < iters) {
                float4 v = vbuf[k];
                #pragma unroll
                for (int j = 0; j < 4; ++j) {
                    uint32_t bits = __float_as_uint(j==0 ? v.x : j==1 ? v.y : j==2 ? v.z : v.w);
                    if ((bits >> SH_A) == vA)
                        atomicAdd(&hh[(bits >> SH_B) & 0x7FFu], 1u);
                }
            }
        }
    } else {
        for (int f = tid; f < n4; f += 1024) {
            float4 v = s4[f];
            #pragma unroll
            for (int j = 0; j < 4; ++j) {
                uint32_t bits = __float_as_uint(j==0 ? v.x : j==1 ? v.y : j==2 ? v.z : v.w);
                if ((bits >> SH_A) == vA)
                    atomicAdd(&hh[(bits >> SH_B) & 0x7FFu], 1u);
            }
        }
    }
    crossing2048(hh, remA, res);
    const uint32_t t_lo = (vA << SH_A) | (res[0] << SH_B);

    // ---- init pad, then gather (wave-aggregated position assignment)
    for (int i = tid; i < CAND_CAP; i += 1024) cand[i] = ~0ull;
    __syncthreads();
    if (reg_path) {
        #pragma unroll
        for (int k = 0; k < MAXIT; ++k) {
            if (k < iters) {
                float4 v = vbuf[k];
                int f = tid + k * 1024;
                #pragma unroll
                for (int j = 0; j < 4; ++j) {
                    uint32_t bits = __float_as_uint(j==0 ? v.x : j==1 ? v.y : j==2 ? v.z : v.w);
                    bool hit = (bits >= t_lo);
                    unsigned long long m = __ballot(hit);
                    if (m) {
                        int ldr = __ffsll(m) - 1;
                        uint32_t base = 0;
                        if (lane == ldr) base = atomicAdd(&sh_cnt, (uint32_t)__popcll(m));
                        base = __shfl(base, ldr);
                        if (hit) {
                            uint32_t pos = base + (uint32_t)__popcll(m & ((1ull << lane) - 1ull));
                            if (pos < CAND_CAP)
                                cand[pos] = ((uint64_t)(~bits) << 32) | (uint64_t)(uint32_t)(4*f + j);
                        }
                    }
                }
            } else {
                // keep wave convergent for ballots in the k<iters branch
            }
        }
    } else {
        for (int f = tid; f < n4; f += 1024) {
            float4 v = s4[f];
            #pragma unroll
            for (int j = 0; j < 4; ++j) {
                uint32_t bits = __float_as_uint(j==0 ? v.x : j==1 ? v.y : j==2 ? v.z : v.w);
                if (bits >= t_lo) {
                    uint32_t pos = atomicAdd(&sh_cnt, 1u);
                    if (pos < CAND_CAP)
                        cand[pos] = ((uint64_t)(~bits) << 32) | (uint64_t)(uint32_t)(4*f + j);
                }
            }
        }
    }
    __syncthreads();
    uint32_t G = sh_cnt;
    if (G > CAND_CAP) G = CAND_CAP;

    // ---- bitonic sort ascending over 2048 keys: (~bits, idx) => score desc, idx asc
    for (unsigned k = 2; k <= CAND_CAP; k <<= 1) {
        for (unsigned j = k >> 1; j > 0; j >>= 1) {
            for (unsigned i = tid; i < CAND_CAP; i += 1024) {
                unsigned ixj = i ^ j;
                if (ixj > i) {
                    uint64_t a = cand[i], c2 = cand[ixj];
                    bool up = ((i & k) == 0);
                    if ((a > c2) == up) { cand[i] = c2; cand[ixj] = a; }
                }
            }
            __syncthreads();
        }
    }

    // ---- decode + write: sorted position IS the output rank
    const float wy1 = window[0], wx1 = window[1], wy2 = window[2], wx2 = window[3];
    const int BK = B * KSEL;
    float* o_ai = out;             // [B,K,2] (b, idx)
    float* o_bx = out + 2 * BK;    // [B,K,4]
    float* o_cl = out + 6 * BK;
    float* o_sc = out + 7 * BK;
    float* o_vd = out + 8 * BK;

    const uint32_t W = (G < KSEL) ? G : KSEL;
    for (uint32_t r = tid; r < W; r += 1024) {
        const uint64_t kc = cand[r];
        if (kc == ~0ull) continue;

        uint32_t idx   = (uint32_t)kc;
        uint32_t sbits = ~(uint32_t)(kc >> 32);
        float score    = __uint_as_float(sbits);

        size_t base = (size_t)b * N + idx;
        const float4 a = *reinterpret_cast<const float4*>(anchors + base * 4);
        const float4 o = *reinterpret_cast<const float4*>(offsets + base * 4);

        float h  = a.z - a.x;
        float w  = a.w - a.y;
        float cy = a.x + 0.5f * h + o.x * h;
        float cx = a.y + 0.5f * w + o.y * w;
        float hh2 = h * expf(o.z);
        float ww  = w * expf(o.w);
        float y1 = fminf(fmaxf(cy - 0.5f * hh2, wy1), wy2);
        float x1 = fminf(fmaxf(cx - 0.5f * ww,  wx1), wx2);
        float y2 = fminf(fmaxf(cy + 0.5f * hh2, wy1), wy2);
        float x2 = fminf(fmaxf(cx + 0.5f * ww,  wx1), wx2);

        int ok = b * KSEL + (int)r;
        o_ai[ok*2 + 0] = (float)b;
        o_ai[ok*2 + 1] = (float)idx;
        o_bx[ok*4 + 0] = y1;
        o_bx[ok*4 + 1] = x1;
        o_bx[ok*4 + 2] = y2;
        o_bx[ok*4 + 3] = x2;
        o_cl[ok] = (float)cls_ws[base];
        o_sc[ok] = score;
        o_vd[ok] = (score > CONF_T) ? 1.0f : 0.0f;
    }
}

extern "C" void kernel_launch(void* const* d_in, const int* in_sizes, int n_in,
                              void* d_out, int out_size, void* d_ws, size_t ws_size,
                              hipStream_t stream)
{
    const float* anchors = (const float*)d_in[0];
    const float* probs   = (const float*)d_in[1];
    const float* offsets = (const float*)d_in[2];
    const float* window  = (const float*)d_in[3];

    const int B = out_size / (9 * KSEL);
    const int N = in_sizes[0] / (B * 4);
    const int total = B * N;

    float*    sc    = (float*)d_ws;
    int*      cls   = (int*)((char*)d_ws + (size_t)total * 4);
    uint32_t* histA = (uint32_t*)((char*)d_ws + (size_t)total * 8);
    const int nhist = B * 2048;

    hipLaunchKernelGGL(zero_kernel, dim3((nhist + 255) / 256), dim3(256), 0, stream,
                       histA, nhist);

    hipLaunchKernelGGL(score_argmax_hist_kernel,
                       dim3((total + ROWS - 1) / ROWS), dim3(T1), 0, stream,
                       probs, sc, cls, histA, total, N);

    hipLaunchKernelGGL(final_select_kernel, dim3(B), dim3(1024), 0, stream,
                       sc, cls, histA, anchors, offsets, window,
                       (float*)d_out, N, B);
}

// Round 22
// 81.990 us; speedup vs baseline: 5.7517x; 1.0749x over previous
//
#include <hip/hip_runtime.h>
#include <hip/hip_bf16.h>
#include <stdint.h>

#define CONF_T 0.05f
#define KSEL 1000
#define CAND_CAP 2048
#define ROWS 128
#define T1 256
#define SH_A 21
#define SH_B 10
#define MAXIT 16

// ---------------- Kernel 1: LDS-staged coalesced argmax (verified core) ----------------
__global__ __launch_bounds__(T1) void score_argmax_kernel(
    const float* __restrict__ probs, float* __restrict__ sc, int* __restrict__ cls,
    int total)
{
    __shared__ float tile[ROWS * 81];
    const int r0  = blockIdx.x * ROWS;
    const int tid = threadIdx.x;
    const int rows_here = min(ROWS, total - r0);

    const float4* src = reinterpret_cast<const float4*>(probs + (size_t)r0 * 80);
    const int nf4 = rows_here * 20;
    for (int f = tid; f < nf4; f += T1) {
        float4 v = src[f];
        int fo  = f * 4;
        int row = fo / 80;
        int col = fo - row * 80;
        float* dst = &tile[row * 81 + col];
        dst[0] = v.x; dst[1] = v.y; dst[2] = v.z; dst[3] = v.w;
    }
    __syncthreads();

    if (tid < rows_here) {
        const float* row = &tile[tid * 81];
        float best = row[0]; int bc = 0;
        #pragma unroll
        for (int j = 1; j < 80; ++j) {
            float v = row[j];
            if (v > best) { best = v; bc = j; }   // first-max-wins
        }
        sc[r0 + tid]  = best;
        cls[r0 + tid] = bc;
    }
}

// ---- wave-parallel crossing over 2048 LDS bins (verified) ----
__device__ __forceinline__ void crossing2048(
    const uint32_t* __restrict__ hh, uint32_t rem, volatile uint32_t* __restrict__ res)
{
    __syncthreads();
    if (threadIdx.x < 64) {
        const int lane = threadIdx.x;
        uint32_t s = 0;
        #pragma unroll 8
        for (int j = 0; j < 32; ++j) s += hh[lane * 32 + j];
        uint32_t suf = s;
        #pragma unroll
        for (int off = 1; off < 64; off <<= 1) {
            uint32_t t = __shfl_down(suf, off);
            if (lane + off < 64) suf += t;
        }
        unsigned long long m = __ballot(suf >= rem);
        int L = (m == 0) ? 0 : (63 - __clzll(m));
        uint32_t cum_above = (L < 63) ? __shfl(suf, L + 1) : 0u;

        uint32_t binv = (lane < 32) ? hh[L * 32 + lane] : 0u;
        uint32_t suf2 = binv;
        #pragma unroll
        for (int off = 1; off < 32; off <<= 1) {
            uint32_t t = __shfl_down(suf2, off);
            if (lane + off < 32) suf2 += t;
        }
        unsigned long long m2 = __ballot(lane < 32 && (cum_above + suf2) >= rem);
        int j = (m2 == 0) ? 0 : (63 - __clzll(m2));
        uint32_t above2 = cum_above + ((j < 31) ? __shfl(suf2, j + 1) : 0u);
        if (lane == 0) {
            res[0] = (uint32_t)(L * 32 + j);
            res[1] = rem - above2;
        }
    }
    __syncthreads();
}

// ---------------- Kernel 2: full select (pass-A from registers, no global hist) ----------
__global__ __launch_bounds__(1024) void final_select_kernel(
    const float* __restrict__ scores, const int* __restrict__ cls_ws,
    const float* __restrict__ anchors, const float* __restrict__ offsets,
    const float* __restrict__ window, float* __restrict__ out,
    int N, int B)
{
    const int b    = blockIdx.x;
    const int tid  = threadIdx.x;
    const int lane = tid & 63;

    __shared__ uint32_t hh[2048];
    __shared__ uint32_t res[2];
    __shared__ uint32_t sh_vA, sh_remA, sh_cnt;
    __shared__ uint64_t cand[CAND_CAP];

    const float4* s4 = reinterpret_cast<const float4*>(scores + (size_t)b * N);
    const int n4 = N >> 2;
    const int iters = (n4 - tid + 1023) / 1024;
    const bool reg_path = ((n4 + 1023) / 1024) <= MAXIT;

    float4 vbuf[MAXIT];
    if (reg_path) {
        #pragma unroll
        for (int k = 0; k < MAXIT; ++k) {
            int f = tid + k * 1024;
            if (k < iters) vbuf[k] = s4[f];
        }
    }

    // ---- pass-A histogram (bits[31:21]) with one-round wave aggregation
    for (int i = tid; i < 2048; i += 1024) hh[i] = 0u;
    if (tid == 0) sh_cnt = 0u;
    __syncthreads();
    if (reg_path) {
        #pragma unroll
        for (int k = 0; k < MAXIT; ++k) {
            const bool act = (k < iters);
            float4 v = act ? vbuf[k] : make_float4(0.f, 0.f, 0.f, 0.f);
            #pragma unroll
            for (int j = 0; j < 4; ++j) {
                uint32_t bits = __float_as_uint(j==0 ? v.x : j==1 ? v.y : j==2 ? v.z : v.w);
                uint32_t bin  = bits >> SH_A;
                unsigned long long actm = __ballot(act);
                if (actm) {
                    int ldr = __ffsll(actm) - 1;
                    uint32_t b0 = __shfl(bin, ldr);
                    unsigned long long eq = __ballot(act && bin == b0);
                    if (lane == ldr) atomicAdd(&hh[b0], (uint32_t)__popcll(eq));
                    if (act && bin != b0) atomicAdd(&hh[bin], 1u);
                }
            }
        }
    } else {
        for (int f = tid; f < n4; f += 1024) {
            float4 v = s4[f];
            #pragma unroll
            for (int j = 0; j < 4; ++j) {
                uint32_t bits = __float_as_uint(j==0 ? v.x : j==1 ? v.y : j==2 ? v.z : v.w);
                atomicAdd(&hh[bits >> SH_A], 1u);
            }
        }
    }
    crossing2048(hh, KSEL, res);
    if (tid == 0) { sh_vA = res[0]; sh_remA = res[1]; }
    __syncthreads();
    const uint32_t vA = sh_vA, remA = sh_remA;

    // ---- pass-B histogram (bits[20:10]) over elements matching prefix A
    for (int i = tid; i < 2048; i += 1024) hh[i] = 0u;
    __syncthreads();
    if (reg_path) {
        #pragma unroll
        for (int k = 0; k < MAXIT; ++k) {
            if (k < iters) {
                float4 v = vbuf[k];
                #pragma unroll
                for (int j = 0; j < 4; ++j) {
                    uint32_t bits = __float_as_uint(j==0 ? v.x : j==1 ? v.y : j==2 ? v.z : v.w);
                    if ((bits >> SH_A) == vA)
                        atomicAdd(&hh[(bits >> SH_B) & 0x7FFu], 1u);
                }
            }
        }
    } else {
        for (int f = tid; f < n4; f += 1024) {
            float4 v = s4[f];
            #pragma unroll
            for (int j = 0; j < 4; ++j) {
                uint32_t bits = __float_as_uint(j==0 ? v.x : j==1 ? v.y : j==2 ? v.z : v.w);
                if ((bits >> SH_A) == vA)
                    atomicAdd(&hh[(bits >> SH_B) & 0x7FFu], 1u);
            }
        }
    }
    crossing2048(hh, remA, res);
    const uint32_t t_lo = (vA << SH_A) | (res[0] << SH_B);

    // ---- init pad, then wave-aggregated gather (verified)
    for (int i = tid; i < CAND_CAP; i += 1024) cand[i] = ~0ull;
    __syncthreads();
    if (reg_path) {
        #pragma unroll
        for (int k = 0; k < MAXIT; ++k) {
            if (k < iters) {
                float4 v = vbuf[k];
                int f = tid + k * 1024;
                #pragma unroll
                for (int j = 0; j < 4; ++j) {
                    uint32_t bits = __float_as_uint(j==0 ? v.x : j==1 ? v.y : j==2 ? v.z : v.w);
                    bool hit = (bits >= t_lo);
                    unsigned long long m = __ballot(hit);
                    if (m) {
                        int ldr = __ffsll(m) - 1;
                        uint32_t base = 0;
                        if (lane == ldr) base = atomicAdd(&sh_cnt, (uint32_t)__popcll(m));
                        base = __shfl(base, ldr);
                        if (hit) {
                            uint32_t pos = base + (uint32_t)__popcll(m & ((1ull << lane) - 1ull));
                            if (pos < CAND_CAP)
                                cand[pos] = ((uint64_t)(~bits) << 32) | (uint64_t)(uint32_t)(4*f + j);
                        }
                    }
                }
            }
        }
    } else {
        for (int f = tid; f < n4; f += 1024) {
            float4 v = s4[f];
            #pragma unroll
            for (int j = 0; j < 4; ++j) {
                uint32_t bits = __float_as_uint(j==0 ? v.x : j==1 ? v.y : j==2 ? v.z : v.w);
                if (bits >= t_lo) {
                    uint32_t pos = atomicAdd(&sh_cnt, 1u);
                    if (pos < CAND_CAP)
                        cand[pos] = ((uint64_t)(~bits) << 32) | (uint64_t)(uint32_t)(4*f + j);
                }
            }
        }
    }
    __syncthreads();
    uint32_t G = sh_cnt;
    if (G > CAND_CAP) G = CAND_CAP;

    // ---- bitonic sort ascending: (~bits, idx) => score desc, idx asc (verified)
    for (unsigned k = 2; k <= CAND_CAP; k <<= 1) {
        for (unsigned j = k >> 1; j > 0; j >>= 1) {
            for (unsigned i = tid; i < CAND_CAP; i += 1024) {
                unsigned ixj = i ^ j;
                if (ixj > i) {
                    uint64_t a = cand[i], c2 = cand[ixj];
                    bool up = ((i & k) == 0);
                    if ((a > c2) == up) { cand[i] = c2; cand[ixj] = a; }
                }
            }
            __syncthreads();
        }
    }

    // ---- decode + write: sorted position IS the rank (verified)
    const float wy1 = window[0], wx1 = window[1], wy2 = window[2], wx2 = window[3];
    const int BK = B * KSEL;
    float* o_ai = out;             // [B,K,2] (b, idx)
    float* o_bx = out + 2 * BK;    // [B,K,4]
    float* o_cl = out + 6 * BK;
    float* o_sc = out + 7 * BK;
    float* o_vd = out + 8 * BK;

    const uint32_t W = (G < KSEL) ? G : KSEL;
    for (uint32_t r = tid; r < W; r += 1024) {
        const uint64_t kc = cand[r];
        if (kc == ~0ull) continue;

        uint32_t idx   = (uint32_t)kc;
        uint32_t sbits = ~(uint32_t)(kc >> 32);
        float score    = __uint_as_float(sbits);

        size_t base = (size_t)b * N + idx;
        const float4 a = *reinterpret_cast<const float4*>(anchors + base * 4);
        const float4 o = *reinterpret_cast<const float4*>(offsets + base * 4);

        float h  = a.z - a.x;
        float w  = a.w - a.y;
        float cy = a.x + 0.5f * h + o.x * h;
        float cx = a.y + 0.5f * w + o.y * w;
        float hh2 = h * expf(o.z);
        float ww  = w * expf(o.w);
        float y1 = fminf(fmaxf(cy - 0.5f * hh2, wy1), wy2);
        float x1 = fminf(fmaxf(cx - 0.5f * ww,  wx1), wx2);
        float y2 = fminf(fmaxf(cy + 0.5f * hh2, wy1), wy2);
        float x2 = fminf(fmaxf(cx + 0.5f * ww,  wx1), wx2);

        int ok = b * KSEL + (int)r;
        o_ai[ok*2 + 0] = (float)b;
        o_ai[ok*2 + 1] = (float)idx;
        o_bx[ok*4 + 0] = y1;
        o_bx[ok*4 + 1] = x1;
        o_bx[ok*4 + 2] = y2;
        o_bx[ok*4 + 3] = x2;
        o_cl[ok] = (float)cls_ws[base];
        o_sc[ok] = score;
        o_vd[ok] = (score > CONF_T) ? 1.0f : 0.0f;
    }
}

extern "C" void kernel_launch(void* const* d_in, const int* in_sizes, int n_in,
                              void* d_out, int out_size, void* d_ws, size_t ws_size,
                              hipStream_t stream)
{
    const float* anchors = (const float*)d_in[0];
    const float* probs   = (const float*)d_in[1];
    const float* offsets = (const float*)d_in[2];
    const float* window  = (const float*)d_in[3];

    const int B = out_size / (9 * KSEL);
    const int N = in_sizes[0] / (B * 4);
    const int total = B * N;

    float* sc  = (float*)d_ws;
    int*   cls = (int*)((char*)d_ws + (size_t)total * 4);

    hipLaunchKernelGGL(score_argmax_kernel,
                       dim3((total + ROWS - 1) / ROWS), dim3(T1), 0, stream,
                       probs, sc, cls, total);

    hipLaunchKernelGGL(final_select_kernel, dim3(B), dim3(1024), 0, stream,
                       sc, cls, anchors, offsets, window,
                       (float*)d_out, N, B);
}